// Round 17
// baseline (45.351 us; speedup 1.0000x reference)
//
#include <hip/hip_runtime.h>

#define N_Q   50000
#define N_S   50000
#define M_NB  32
#define K_PTS 15
#define CIN   64
#define COUT  64
#define WPB   2
#define REP   4      // gather-phase amplification: 1 real + (REP-1) dummy probes

// === R13 kernel + gather amplification (ablation instrumentation) ===
// The REP-1 dummy gathers are real random 12B reads with the same statistics
// as the true support gather; their results feed an asm sink so they cannot
// be dead-code-eliminated, and they do not touch the computed output.
__global__ __launch_bounds__(128) void kpconv_fused4(
    const float* __restrict__ query,     // [N,3]
    const float* __restrict__ support,   // [N0,3]
    const int*   __restrict__ neighbors, // [N,M]
    const float* __restrict__ x,         // [N0,CIN]
    const float* __restrict__ kpts,      // [K,3]
    const float* __restrict__ weight,    // [K,CIN,COUT]
    float*       __restrict__ out)       // [N,COUT]
{
    __shared__ float s_kx[K_PTS], s_ky[K_PTS], s_kz[K_PTS], s_kk[K_PTS];
    __shared__ float s_bc[WPB][CIN];

    const int tid = threadIdx.x;
    if (tid < K_PTS) {
        float kx = kpts[tid * 3 + 0];
        float ky = kpts[tid * 3 + 1];
        float kz = kpts[tid * 3 + 2];
        s_kx[tid] = kx; s_ky[tid] = ky; s_kz[tid] = kz;
        s_kk[tid] = kx * kx + ky * ky + kz * kz;   // same 3-term fp32 sum as ref
    }
    __syncthreads();

    const int wv   = tid >> 6;
    const int lane = tid & 63;
    const int base = blockIdx.x * (WPB * 2) + wv * 2;
    const int h    = lane >> 5;
    const int n    = base + h;
    const int m    = lane & 31;

    const int idx = neighbors[n * M_NB + m];

    float dx = 0.f, dy = 0.f, dz = 0.f, nn = 1e30f;
    if (idx < N_S) {
        dx = support[idx * 3 + 0] - query[n * 3 + 0];
        dy = support[idx * 3 + 1] - query[n * 3 + 1];
        dz = support[idx * 3 + 2] - query[n * 3 + 2];
        nn = dx * dx + dy * dy + dz * dz;
    }

    // ---- amplification probes: REP-1 extra random gathers, same predicate ----
    float sink = 0.f;
    #pragma unroll
    for (int r = 1; r < REP; ++r) {
        int vidx = idx + r * 9973;                 // decorrelated random index
        if (vidx >= N_S) vidx -= N_S;              // idx<=N_S, r<=3 -> one sub
        float gx = 0.f, gy = 0.f, gz = 0.f;
        if (idx < N_S) {                           // same predicate as real one
            gx = support[vidx * 3 + 0];
            gy = support[vidx * 3 + 1];
            gz = support[vidx * 3 + 2];
        }
        sink += gx * gx + gy * gy + gz * gz;
    }
    asm volatile("" :: "v"(sink));                 // keep-alive, no output effect

    const int og = (lane & 15) * 4;
    const int cg = lane >> 4;

    float4 toutA = make_float4(0.f, 0.f, 0.f, 0.f);
    float4 toutB = make_float4(0.f, 0.f, 0.f, 0.f);

    if (__ballot(nn < 0.0101f)) {
        for (int k = 0; k < K_PTS; ++k) {
            float w = 0.f;
            if (nn < 0.0101f) {
                float dot = dx * s_kx[k] + dy * s_ky[k] + dz * s_kz[k];
                float sq  = fmaxf(nn - 2.f * dot + s_kk[k], 0.f);
                if (sq < 0.0025f)
                    w = 1.f - sqrtf(sq) * 20.f;
            }
            const unsigned long long em = __ballot(w > 0.f);
            if (!em) continue;

            const float* wk = weight + (size_t)k * CIN * COUT;
            const float* wq = wk + cg * COUT + og;

            unsigned emA = (unsigned)(em & 0xffffffffull);
            if (emA) {
                float racc = 0.f;
                do {
                    const int src = __builtin_ctz(emA); emA &= emA - 1;
                    const float wsrc = __shfl(w,   src);
                    const int   isrc = __shfl(idx, src);
                    racc = fmaf(wsrc, x[(size_t)isrc * CIN + lane], racc);
                } while (emA);
                s_bc[wv][lane] = racc;
                asm volatile("" ::: "memory");
                float4 a0 = make_float4(0.f,0.f,0.f,0.f);
                float4 a1 = make_float4(0.f,0.f,0.f,0.f);
                #pragma unroll
                for (int i = 0; i < 16; i += 2) {
                    const float4 v0 = *(const float4*)(wq + (i + 0) * 4 * COUT);
                    const float4 v1 = *(const float4*)(wq + (i + 1) * 4 * COUT);
                    const float xc0 = s_bc[wv][cg + 4 * i];
                    const float xc1 = s_bc[wv][cg + 4 * i + 4];
                    a0.x = fmaf(xc0, v0.x, a0.x); a0.y = fmaf(xc0, v0.y, a0.y);
                    a0.z = fmaf(xc0, v0.z, a0.z); a0.w = fmaf(xc0, v0.w, a0.w);
                    a1.x = fmaf(xc1, v1.x, a1.x); a1.y = fmaf(xc1, v1.y, a1.y);
                    a1.z = fmaf(xc1, v1.z, a1.z); a1.w = fmaf(xc1, v1.w, a1.w);
                }
                a0.x += a1.x; a0.y += a1.y; a0.z += a1.z; a0.w += a1.w;
                a0.x += __shfl_xor(a0.x, 16); a0.y += __shfl_xor(a0.y, 16);
                a0.z += __shfl_xor(a0.z, 16); a0.w += __shfl_xor(a0.w, 16);
                a0.x += __shfl_xor(a0.x, 32); a0.y += __shfl_xor(a0.y, 32);
                a0.z += __shfl_xor(a0.z, 32); a0.w += __shfl_xor(a0.w, 32);
                toutA.x += a0.x; toutA.y += a0.y;
                toutA.z += a0.z; toutA.w += a0.w;
                asm volatile("" ::: "memory");
            }

            unsigned emB = (unsigned)(em >> 32);
            if (emB) {
                float racc = 0.f;
                do {
                    const int src = 32 + __builtin_ctz(emB); emB &= emB - 1;
                    const float wsrc = __shfl(w,   src);
                    const int   isrc = __shfl(idx, src);
                    racc = fmaf(wsrc, x[(size_t)isrc * CIN + lane], racc);
                } while (emB);
                s_bc[wv][lane] = racc;
                asm volatile("" ::: "memory");
                float4 a0 = make_float4(0.f,0.f,0.f,0.f);
                float4 a1 = make_float4(0.f,0.f,0.f,0.f);
                #pragma unroll
                for (int i = 0; i < 16; i += 2) {
                    const float4 v0 = *(const float4*)(wq + (i + 0) * 4 * COUT);
                    const float4 v1 = *(const float4*)(wq + (i + 1) * 4 * COUT);
                    const float xc0 = s_bc[wv][cg + 4 * i];
                    const float xc1 = s_bc[wv][cg + 4 * i + 4];
                    a0.x = fmaf(xc0, v0.x, a0.x); a0.y = fmaf(xc0, v0.y, a0.y);
                    a0.z = fmaf(xc0, v0.z, a0.z); a0.w = fmaf(xc0, v0.w, a0.w);
                    a1.x = fmaf(xc1, v1.x, a1.x); a1.y = fmaf(xc1, v1.y, a1.y);
                    a1.z = fmaf(xc1, v1.z, a1.z); a1.w = fmaf(xc1, v1.w, a1.w);
                }
                a0.x += a1.x; a0.y += a1.y; a0.z += a1.z; a0.w += a1.w;
                a0.x += __shfl_xor(a0.x, 16); a0.y += __shfl_xor(a0.y, 16);
                a0.z += __shfl_xor(a0.z, 16); a0.w += __shfl_xor(a0.w, 16);
                a0.x += __shfl_xor(a0.x, 32); a0.y += __shfl_xor(a0.y, 32);
                a0.z += __shfl_xor(a0.z, 32); a0.w += __shfl_xor(a0.w, 32);
                toutB.x += a0.x; toutB.y += a0.y;
                toutB.z += a0.z; toutB.w += a0.w;
                asm volatile("" ::: "memory");
            }
        }
    }

    float4* rowA = (float4*)(out + (size_t)(base + 0) * COUT);
    float4* rowB = (float4*)(out + (size_t)(base + 1) * COUT);
    if (lane < 16)       rowA[lane]      = toutA;
    else if (lane < 32)  rowB[lane - 16] = toutB;
}

extern "C" void kernel_launch(void* const* d_in, const int* in_sizes, int n_in,
                              void* d_out, int out_size, void* d_ws, size_t ws_size,
                              hipStream_t stream) {
    const float* query     = (const float*)d_in[0];
    const float* support   = (const float*)d_in[1];
    const int*   neighbors = (const int*)  d_in[2];
    const float* x         = (const float*)d_in[3];
    const float* kpts      = (const float*)d_in[4];
    const float* weight    = (const float*)d_in[5];
    float*       out       = (float*)d_out;

    kpconv_fused4<<<N_Q / 4, 128, 0, stream>>>(
        query, support, neighbors, x, kpts, weight, out);
}

// Round 18
// 29.196 us; speedup vs baseline: 1.5533x; 1.5533x over previous
//
#include <hip/hip_runtime.h>

#define N_Q   50000
#define N_S   50000
#define M_NB  32
#define K_PTS 15
#define CIN   64
#define COUT  64
#define WPB   2
#define THR   0.0101f   // ||nb||^2 bound for any w>0 (exact: 0.009901)

// Event processing: racc gather of weighted feature row (using prefetched
// rows where possible), then R13's wide GEMV (lane owns quad og=(lane&15)*4,
// c-subset cg=lane>>4; 16 dwordx4 loads, 2 FMA chains, shfl_xor reduce).
__device__ __forceinline__ void do_event(
    unsigned em, int laneoff, float w, int idx,
    float* bc, const float* wq, int cg,
    const float* __restrict__ x, int lane, float4& tout,
    int s0, int s1, int s2, int s3,
    float xr0, float xr1, float xr2, float xr3)
{
    float racc = 0.f;
    do {
        const int src = laneoff + __builtin_ctz(em); em &= em - 1;
        const float wsrc = __shfl(w, src);
        float xv;                                   // wave-uniform selection
        if      (src == s0) xv = xr0;
        else if (src == s1) xv = xr1;
        else if (src == s2) xv = xr2;
        else if (src == s3) xv = xr3;
        else xv = x[(size_t)__shfl(idx, src) * CIN + lane];  // rare (>4 close)
        racc = fmaf(wsrc, xv, racc);
    } while (em);
    bc[lane] = racc;
    asm volatile("" ::: "memory");
    float4 a0 = make_float4(0.f, 0.f, 0.f, 0.f);
    float4 a1 = make_float4(0.f, 0.f, 0.f, 0.f);
    #pragma unroll
    for (int i = 0; i < 16; i += 2) {
        const float4 v0 = *(const float4*)(wq + (i + 0) * 4 * COUT);
        const float4 v1 = *(const float4*)(wq + (i + 1) * 4 * COUT);
        const float xc0 = bc[cg + 4 * i];
        const float xc1 = bc[cg + 4 * i + 4];
        a0.x = fmaf(xc0, v0.x, a0.x); a0.y = fmaf(xc0, v0.y, a0.y);
        a0.z = fmaf(xc0, v0.z, a0.z); a0.w = fmaf(xc0, v0.w, a0.w);
        a1.x = fmaf(xc1, v1.x, a1.x); a1.y = fmaf(xc1, v1.y, a1.y);
        a1.z = fmaf(xc1, v1.z, a1.z); a1.w = fmaf(xc1, v1.w, a1.w);
    }
    a0.x += a1.x; a0.y += a1.y; a0.z += a1.z; a0.w += a1.w;
    a0.x += __shfl_xor(a0.x, 16); a0.y += __shfl_xor(a0.y, 16);
    a0.z += __shfl_xor(a0.z, 16); a0.w += __shfl_xor(a0.w, 16);
    a0.x += __shfl_xor(a0.x, 32); a0.y += __shfl_xor(a0.y, 32);
    a0.z += __shfl_xor(a0.z, 32); a0.w += __shfl_xor(a0.w, 32);
    tout.x += a0.x; tout.y += a0.y; tout.z += a0.z; tout.w += a0.w;
    asm volatile("" ::: "memory");
}

// R13 structure: one wave per TWO query points (A = lanes 0-31, B = 32-63),
// single dispatch, no workspace. NEW: x-rows of the (usually 1-3) close pairs
// are prefetched immediately after the close ballot, so their cold HBM misses
// overlap each other and the k-loop VALU work, and each row is loaded once.
__global__ __launch_bounds__(128) void kpconv_fused7(
    const float* __restrict__ query,     // [N,3]
    const float* __restrict__ support,   // [N0,3]
    const int*   __restrict__ neighbors, // [N,M]
    const float* __restrict__ x,         // [N0,CIN]
    const float* __restrict__ kpts,      // [K,3]
    const float* __restrict__ weight,    // [K,CIN,COUT]
    float*       __restrict__ out)       // [N,COUT]
{
    __shared__ float s_kx[K_PTS], s_ky[K_PTS], s_kz[K_PTS], s_kk[K_PTS];
    __shared__ float s_bc[WPB][CIN];

    const int tid = threadIdx.x;
    if (tid < K_PTS) {
        float kx = kpts[tid * 3 + 0];
        float ky = kpts[tid * 3 + 1];
        float kz = kpts[tid * 3 + 2];
        s_kx[tid] = kx; s_ky[tid] = ky; s_kz[tid] = kz;
        s_kk[tid] = kx * kx + ky * ky + kz * kz;   // same 3-term fp32 sum as ref
    }
    __syncthreads();

    const int wv   = tid >> 6;
    const int lane = tid & 63;
    const int base = blockIdx.x * (WPB * 2) + wv * 2;  // grid = N_Q/4 exactly
    const int h    = lane >> 5;
    const int n    = base + h;
    const int m    = lane & 31;

    const int idx = neighbors[n * M_NB + m];      // coalesced (2 rows/wave)

    float dx = 0.f, dy = 0.f, dz = 0.f, nn = 1e30f;
    if (idx < N_S) {                              // idx==N_S: shadow, w==0
        dx = support[idx * 3 + 0] - query[n * 3 + 0];
        dy = support[idx * 3 + 1] - query[n * 3 + 1];
        dz = support[idx * 3 + 2] - query[n * 3 + 2];
        nn = dx * dx + dy * dy + dz * dz;
    }

    const int og = (lane & 15) * 4;
    const int cg = lane >> 4;

    float4 toutA = make_float4(0.f, 0.f, 0.f, 0.f);
    float4 toutB = make_float4(0.f, 0.f, 0.f, 0.f);

    const unsigned long long cb = __ballot(nn < THR);   // close-pair ballot

    if (cb) {                                     // ~23% of waves
        // ---- prefetch up to 4 close x-rows (wave-uniform srcs, MLP=4) ----
        unsigned long long t = cb;
        int s0 = -1, s1 = -1, s2 = -1, s3 = -1;
        if (t) { s0 = __ffsll(t) - 1; t &= t - 1; }
        if (t) { s1 = __ffsll(t) - 1; t &= t - 1; }
        if (t) { s2 = __ffsll(t) - 1; t &= t - 1; }
        if (t) { s3 = __ffsll(t) - 1; t &= t - 1; }
        float xr0 = 0.f, xr1 = 0.f, xr2 = 0.f, xr3 = 0.f;
        if (s0 >= 0) xr0 = x[(size_t)__shfl(idx, s0) * CIN + lane];
        if (s1 >= 0) xr1 = x[(size_t)__shfl(idx, s1) * CIN + lane];
        if (s2 >= 0) xr2 = x[(size_t)__shfl(idx, s2) * CIN + lane];
        if (s3 >= 0) xr3 = x[(size_t)__shfl(idx, s3) * CIN + lane];

        for (int k = 0; k < K_PTS; ++k) {
            float w = 0.f;
            if (nn < THR) {
                float dot = dx * s_kx[k] + dy * s_ky[k] + dz * s_kz[k];
                float sq  = fmaxf(nn - 2.f * dot + s_kk[k], 0.f);  // ref expansion
                if (sq < 0.0025f)                  // sqrt(sq) < 0.05 => w > 0
                    w = 1.f - sqrtf(sq) * 20.f;    // 1/0.05 == 20 exactly
            }
            const unsigned long long em = __ballot(w > 0.f);
            if (!em) continue;                     // common: k has no hits

            const float* wq = weight + (size_t)k * CIN * COUT + cg * COUT + og;

            unsigned mm;
            if ((mm = (unsigned)(em & 0xffffffffull)))
                do_event(mm,  0, w, idx, s_bc[wv], wq, cg, x, lane, toutA,
                         s0, s1, s2, s3, xr0, xr1, xr2, xr3);
            if ((mm = (unsigned)(em >> 32)))
                do_event(mm, 32, w, idx, s_bc[wv], wq, cg, x, lane, toutB,
                         s0, s1, s2, s3, xr0, xr1, xr2, xr3);
        }
    }

    float4* rowA = (float4*)(out + (size_t)(base + 0) * COUT);
    float4* rowB = (float4*)(out + (size_t)(base + 1) * COUT);
    if (lane < 16)       rowA[lane]      = toutA;
    else if (lane < 32)  rowB[lane - 16] = toutB;
}

extern "C" void kernel_launch(void* const* d_in, const int* in_sizes, int n_in,
                              void* d_out, int out_size, void* d_ws, size_t ws_size,
                              hipStream_t stream) {
    const float* query     = (const float*)d_in[0];
    const float* support   = (const float*)d_in[1];
    const int*   neighbors = (const int*)  d_in[2];
    const float* x         = (const float*)d_in[3];
    const float* kpts      = (const float*)d_in[4];
    const float* weight    = (const float*)d_in[5];
    float*       out       = (float*)d_out;

    kpconv_fused7<<<N_Q / 4, 128, 0, stream>>>(    // 12500 blocks, 2 waves
        query, support, neighbors, x, kpts, weight, out);
}

// Round 19
// 27.776 us; speedup vs baseline: 1.6328x; 1.0511x over previous
//
#include <hip/hip_runtime.h>

#define N_Q   50000
#define N_S   50000
#define M_NB  32
#define K_PTS 15
#define CIN   64
#define COUT  64
#define WPB   2
#define THR   0.0101f   // ||nb||^2 bound for any w>0 (exact: 0.009901)

// Event: racc gather of the weighted feature row, then wide GEMV.
// x-row base is hoisted to SGPR (readfirstlane) -> saddr-form vector load.
__device__ __forceinline__ void do_event(
    unsigned em, int laneoff, float w, int idx,
    float* bc, const float* wq, int cg,
    const float* __restrict__ x, int lane, float4& tout)
{
    float racc = 0.f;
    do {
        const int src = laneoff + __builtin_ctz(em); em &= em - 1;
        const float wsrc = __shfl(w, src);
        const int   isrc = __builtin_amdgcn_readfirstlane(__shfl(idx, src));
        racc = fmaf(wsrc, x[(size_t)isrc * CIN + lane], racc);
    } while (em);
    bc[lane] = racc;
    asm volatile("" ::: "memory");
    float4 a0 = make_float4(0.f, 0.f, 0.f, 0.f);
    float4 a1 = make_float4(0.f, 0.f, 0.f, 0.f);
    #pragma unroll
    for (int i = 0; i < 16; i += 2) {
        const float4 v0 = *(const float4*)(wq + (i + 0) * 4 * COUT);
        const float4 v1 = *(const float4*)(wq + (i + 1) * 4 * COUT);
        const float xc0 = bc[cg + 4 * i];
        const float xc1 = bc[cg + 4 * i + 4];
        a0.x = fmaf(xc0, v0.x, a0.x); a0.y = fmaf(xc0, v0.y, a0.y);
        a0.z = fmaf(xc0, v0.z, a0.z); a0.w = fmaf(xc0, v0.w, a0.w);
        a1.x = fmaf(xc1, v1.x, a1.x); a1.y = fmaf(xc1, v1.y, a1.y);
        a1.z = fmaf(xc1, v1.z, a1.z); a1.w = fmaf(xc1, v1.w, a1.w);
    }
    a0.x += a1.x; a0.y += a1.y; a0.z += a1.z; a0.w += a1.w;
    a0.x += __shfl_xor(a0.x, 16); a0.y += __shfl_xor(a0.y, 16);
    a0.z += __shfl_xor(a0.z, 16); a0.w += __shfl_xor(a0.w, 16);
    a0.x += __shfl_xor(a0.x, 32); a0.y += __shfl_xor(a0.y, 32);
    a0.z += __shfl_xor(a0.z, 32); a0.w += __shfl_xor(a0.w, 32);
    tout.x += a0.x; tout.y += a0.y; tout.z += a0.z; tout.w += a0.w;
    asm volatile("" ::: "memory");
}

// R13 structure (champion): one wave per TWO query points (A = lanes 0-31,
// B = lanes 32-63), single dispatch, no workspace.
// NEW: query coordinates are loaded through the SCALAR path. The wave id is
// forced uniform via readfirstlane, so `base` is SGPR-resident and the six
// query loads compile to s_load (SMEM) instead of six 64-lane vector loads —
// removing ~384 of ~470 TA lane-address cycles per wave.
__global__ __launch_bounds__(128) void kpconv_fused8(
    const float* __restrict__ query,     // [N,3]
    const float* __restrict__ support,   // [N0,3]
    const int*   __restrict__ neighbors, // [N,M]
    const float* __restrict__ x,         // [N0,CIN]
    const float* __restrict__ kpts,      // [K,3]
    const float* __restrict__ weight,    // [K,CIN,COUT]
    float*       __restrict__ out)       // [N,COUT]
{
    __shared__ float s_kx[K_PTS], s_ky[K_PTS], s_kz[K_PTS], s_kk[K_PTS];
    __shared__ float s_bc[WPB][CIN];

    const int tid = threadIdx.x;
    if (tid < K_PTS) {
        float kx = kpts[tid * 3 + 0];
        float ky = kpts[tid * 3 + 1];
        float kz = kpts[tid * 3 + 2];
        s_kx[tid] = kx; s_ky[tid] = ky; s_kz[tid] = kz;
        s_kk[tid] = kx * kx + ky * ky + kz * kz;   // same 3-term fp32 sum as ref
    }
    __syncthreads();

    const int wv   = __builtin_amdgcn_readfirstlane(tid >> 6);  // uniform SGPR
    const int lane = tid & 63;
    const int base = blockIdx.x * (WPB * 2) + wv * 2;  // SGPR-uniform
    const int h    = lane >> 5;                    // half: 0 -> A, 1 -> B
    const int n    = base + h;
    const int m    = lane & 31;

    // scalar (SMEM) query loads: uniform addresses, zero TA cost
    const float qxA = query[(base + 0) * 3 + 0];
    const float qyA = query[(base + 0) * 3 + 1];
    const float qzA = query[(base + 0) * 3 + 2];
    const float qxB = query[(base + 1) * 3 + 0];
    const float qyB = query[(base + 1) * 3 + 1];
    const float qzB = query[(base + 1) * 3 + 2];
    const float qx = h ? qxB : qxA;                // v_cndmask
    const float qy = h ? qyB : qyA;
    const float qz = h ? qzB : qzA;

    const int idx = neighbors[n * M_NB + m];       // coalesced (2 rows/wave)

    float dx = 0.f, dy = 0.f, dz = 0.f, nn = 1e30f;
    if (idx < N_S) {                               // idx==N_S: shadow, w==0
        dx = support[idx * 3 + 0] - qx;
        dy = support[idx * 3 + 1] - qy;
        dz = support[idx * 3 + 2] - qz;
        nn = dx * dx + dy * dy + dz * dz;
    }

    const int og = (lane & 15) * 4;
    const int cg = lane >> 4;

    float4 toutA = make_float4(0.f, 0.f, 0.f, 0.f);
    float4 toutB = make_float4(0.f, 0.f, 0.f, 0.f);

    if (__ballot(nn < THR)) {                      // ~23% of waves
        for (int k = 0; k < K_PTS; ++k) {
            float w = 0.f;
            if (nn < THR) {
                float dot = dx * s_kx[k] + dy * s_ky[k] + dz * s_kz[k];
                float sq  = fmaxf(nn - 2.f * dot + s_kk[k], 0.f);  // ref expansion
                if (sq < 0.0025f)                   // sqrt(sq) < 0.05 => w > 0
                    w = 1.f - sqrtf(sq) * 20.f;     // 1/0.05 == 20 exactly
            }
            const unsigned long long em = __ballot(w > 0.f);
            if (!em) continue;                      // common: k has no hits

            const float* wq = weight + (size_t)k * CIN * COUT + cg * COUT + og;

            unsigned mm;
            if ((mm = (unsigned)(em & 0xffffffffull)))
                do_event(mm,  0, w, idx, s_bc[wv], wq, cg, x, lane, toutA);
            if ((mm = (unsigned)(em >> 32)))
                do_event(mm, 32, w, idx, s_bc[wv], wq, cg, x, lane, toutB);
        }
    }

    float4* rowA = (float4*)(out + (size_t)(base + 0) * COUT);
    float4* rowB = (float4*)(out + (size_t)(base + 1) * COUT);
    if (lane < 16)       rowA[lane]      = toutA;
    else if (lane < 32)  rowB[lane - 16] = toutB;
}

extern "C" void kernel_launch(void* const* d_in, const int* in_sizes, int n_in,
                              void* d_out, int out_size, void* d_ws, size_t ws_size,
                              hipStream_t stream) {
    const float* query     = (const float*)d_in[0];
    const float* support   = (const float*)d_in[1];
    const int*   neighbors = (const int*)  d_in[2];
    const float* x         = (const float*)d_in[3];
    const float* kpts      = (const float*)d_in[4];
    const float* weight    = (const float*)d_in[5];
    float*       out       = (float*)d_out;

    kpconv_fused8<<<N_Q / 4, 128, 0, stream>>>(    // 12500 blocks, 2 waves
        query, support, neighbors, x, kpts, weight, out);
}